// Round 20
// baseline (201.484 us; speedup 1.0000x reference)
//
#include <hip/hip_runtime.h>
#include <math.h>

#define L_SEQ 8192
#define DM 512
#define BATCH 4
#define NROWS (BATCH * L_SEQ)  // 32768
#define TAPS 32
#define EPS 1e-5f

typedef __attribute__((ext_vector_type(4))) float f32x4;
typedef __attribute__((ext_vector_type(8))) short bf16x8;
typedef __attribute__((ext_vector_type(4))) short short4v;
typedef __attribute__((ext_vector_type(8))) unsigned short ushort8;

__device__ inline unsigned short f2bf(float f) {
    unsigned u = __float_as_uint(f);
    u += 0x7FFF + ((u >> 16) & 1);   // round-to-nearest-even
    return (unsigned short)(u >> 16);
}

__device__ inline float bf2f(unsigned short u) {
    return __uint_as_float((unsigned)u << 16);
}

__device__ inline float wave_sum(float v) {
#pragma unroll
    for (int m = 32; m >= 1; m >>= 1) v += __shfl_xor(v, m);
    return v;
}

__device__ inline void gload_lds16(const void* g, void* l) {
    __builtin_amdgcn_global_load_lds(
        (const __attribute__((address_space(1))) void*)g,
        (__attribute__((address_space(3))) void*)l, 16, 0, 0);
}

// ---------------------------------------------------------------- taps
__global__ void gen_taps(const float* __restrict__ Ar, const float* __restrict__ Ai,
                         const float* __restrict__ Br, const float* __restrict__ Bi,
                         const float* __restrict__ Cr, const float* __restrict__ Ci,
                         float* __restrict__ taps) {
    int d = blockIdx.x * blockDim.x + threadIdx.x;
    if (d >= DM) return;
    float ar = Ar[d], ai = Ai[d];
    float pr = Cr[d] * Br[d] - Ci[d] * Bi[d];
    float pi = Cr[d] * Bi[d] + Ci[d] * Br[d];
#pragma unroll
    for (int s = 0; s < TAPS; ++s) {
        taps[s * DM + d] = pr;
        float nr = pr * ar - pi * ai;
        pi = pr * ai + pi * ar;
        pr = nr;
    }
}

// ---------------------------------------------------------------- LN1 row stats
__global__ __launch_bounds__(256) void ln_stats(const float* __restrict__ x,
                                                float2* __restrict__ stats) {
    int row = blockIdx.x * 4 + (threadIdx.x >> 6);
    int lane = threadIdx.x & 63;
    const float* xr = x + (size_t)row * DM;
    f32x4 v0 = *(const f32x4*)(xr + lane * 8);
    f32x4 v1 = *(const f32x4*)(xr + lane * 8 + 4);
    float s = v0[0] + v0[1] + v0[2] + v0[3] + v1[0] + v1[1] + v1[2] + v1[3];
    s = wave_sum(s);
    float mean = s * (1.0f / DM);
    float vs = 0.f;
#pragma unroll
    for (int j = 0; j < 4; ++j) { float a = v0[j] - mean; vs += a * a; }
#pragma unroll
    for (int j = 0; j < 4; ++j) { float a = v1[j] - mean; vs += a * a; }
    vs = wave_sum(vs);
    float rstd = rsqrtf(vs * (1.0f / DM) + EPS);
    if (lane == 0) stats[row] = make_float2(mean, rstd);
}

// ---------------------------------------------------------------- LN2 stats from bf16 X2b (big path)
__global__ __launch_bounds__(256) void ln2stats_b(const unsigned short* __restrict__ X2b,
                                                  float2* __restrict__ stats2) {
    int row = blockIdx.x * 4 + (threadIdx.x >> 6);
    int lane = threadIdx.x & 63;
    ushort8 u = *(const ushort8*)(X2b + (size_t)row * DM + lane * 8);
    float v[8];
#pragma unroll
    for (int j = 0; j < 8; ++j) v[j] = bf2f(u[j]);
    float s = 0.f;
#pragma unroll
    for (int j = 0; j < 8; ++j) s += v[j];
    s = wave_sum(s);
    float mean = s * (1.0f / DM);
    float vs = 0.f;
#pragma unroll
    for (int j = 0; j < 8; ++j) { float a = v[j] - mean; vs += a * a; }
    vs = wave_sum(vs);
    float rstd = rsqrtf(vs * (1.0f / DM) + EPS);
    if (lane == 0) stats2[row] = make_float2(mean, rstd);
}

// ---------------------------------------------------------------- LN2 stats from fp32 (fallback path)
__global__ __launch_bounds__(256) void ln2pack(const float* __restrict__ x2,
                                               float2* __restrict__ stats2) {
    int row = blockIdx.x * 4 + (threadIdx.x >> 6);
    int lane = threadIdx.x & 63;
    const float* xr = x2 + (size_t)row * DM;
    f32x4 v0 = *(const f32x4*)(xr + lane * 8);
    f32x4 v1 = *(const f32x4*)(xr + lane * 8 + 4);
    float s = v0[0] + v0[1] + v0[2] + v0[3] + v1[0] + v1[1] + v1[2] + v1[3];
    s = wave_sum(s);
    float mean = s * (1.0f / DM);
    float vs = 0.f;
#pragma unroll
    for (int j = 0; j < 4; ++j) { float a = v0[j] - mean; vs += a * a; }
#pragma unroll
    for (int j = 0; j < 4; ++j) { float a = v1[j] - mean; vs += a * a; }
    vs = wave_sum(vs);
    float rstd = rsqrtf(vs * (1.0f / DM) + EPS);
    if (lane == 0) stats2[row] = make_float2(mean, rstd);
}

// ---------------------------------------------------------------- S4 conv (lean)
// Big path (X2b != null): write bf16 X2b ONLY (out untouched; gemm2 writes it).
// Fallback: write fp32 out.
__global__ __launch_bounds__(256) void s4_conv(
    const float* __restrict__ x, const float2* __restrict__ stats,
    const float* __restrict__ ln1g, const float* __restrict__ ln1b,
    const float* __restrict__ taps, const float* __restrict__ Dvec,
    float* __restrict__ out, unsigned short* __restrict__ X2b) {
    __shared__ __align__(16) float hbuf[96][64];
    __shared__ __align__(16) float kbuf[TAPS][64];
    int tid = threadIdx.x;
    int dc = blockIdx.x * 64;
    int t0 = blockIdx.y * 64;
    int b = blockIdx.z;
    const float* xb = x + (size_t)b * L_SEQ * DM;
    const float2* sb = stats + (size_t)b * L_SEQ;

#pragma unroll
    for (int i = 0; i < 2; ++i) {
        int idx = i * 256 + tid;
        int s = idx >> 4, c4i = (idx & 15) * 4;
        *(f32x4*)&kbuf[s][c4i] = *(const f32x4*)(taps + s * DM + dc + c4i);
    }
    int c4 = (tid & 15) * 4;
    int r0 = tid >> 4;
    f32x4 g4 = *(const f32x4*)(ln1g + dc + c4);
    f32x4 b4 = *(const f32x4*)(ln1b + dc + c4);
#pragma unroll
    for (int i = 0; i < 6; ++i) {
        int r = i * 16 + r0;
        int t = t0 - (TAPS - 1) + r;
        f32x4 h4 = {0.f, 0.f, 0.f, 0.f};
        if (t >= 0 && t < L_SEQ) {
            f32x4 xv = *(const f32x4*)(xb + (size_t)t * DM + dc + c4);
            float2 st = sb[t];
#pragma unroll
            for (int j = 0; j < 4; ++j) h4[j] = g4[j] * (xv[j] - st.x) * st.y + b4[j];
        }
        *(f32x4*)&hbuf[r][c4] = h4;
    }
    __syncthreads();

    int d4 = c4;
    int rbase = r0 * 4;
    f32x4 acc[4] = {{0.f,0.f,0.f,0.f},{0.f,0.f,0.f,0.f},{0.f,0.f,0.f,0.f},{0.f,0.f,0.f,0.f}};
    f32x4 tv[4];
    tv[0] = *(const f32x4*)&kbuf[TAPS - 1][d4];
    tv[1] = (f32x4){0.f,0.f,0.f,0.f};
    tv[2] = tv[1]; tv[3] = tv[1];
#pragma unroll
    for (int jj = 0; jj < TAPS + 3; ++jj) {
        f32x4 h4 = *(const f32x4*)&hbuf[rbase + jj][d4];
#pragma unroll
        for (int i = 0; i < 4; ++i)
#pragma unroll
            for (int j = 0; j < 4; ++j) acc[i][j] += tv[i][j] * h4[j];
        tv[3] = tv[2]; tv[2] = tv[1]; tv[1] = tv[0];
        int snew = TAPS - 2 - jj;
        if (snew >= 0) tv[0] = *(const f32x4*)&kbuf[snew][d4];
        else tv[0] = (f32x4){0.f,0.f,0.f,0.f};
    }

    f32x4 D4 = *(const f32x4*)(Dvec + dc + d4);
#pragma unroll
    for (int i = 0; i < 4; ++i) {
        int t = t0 + rbase + i;
        f32x4 xv = *(const f32x4*)(xb + (size_t)t * DM + dc + d4);
        f32x4 h4 = *(const f32x4*)&hbuf[rbase + i + TAPS - 1][d4];
        f32x4 o;
#pragma unroll
        for (int j = 0; j < 4; ++j) o[j] = xv[j] + acc[i][j] + D4[j] * h4[j];
        size_t rowg = (size_t)(b * L_SEQ + t);
        if (X2b) {
            short4v pb;
#pragma unroll
            for (int j = 0; j < 4; ++j) pb[j] = (short)f2bf(o[j]);
            *(short4v*)(X2b + rowg * DM + dc + d4) = pb;
        } else {
            *(f32x4*)(out + rowg * DM + dc + d4) = o;
        }
    }
}

// ---------------------------------------------------------------- W2 transpose -> bf16
__global__ __launch_bounds__(256) void transpose_bf16(const float* __restrict__ W,
                                                      unsigned short* __restrict__ WT,
                                                      int K, int N) {
    __shared__ float tile[32][33];
    int n0 = blockIdx.x * 32, k0 = blockIdx.y * 32;
    int tx = threadIdx.x & 31, ty = threadIdx.x >> 5;  // 32 x 8
#pragma unroll
    for (int i = 0; i < 32; i += 8)
        tile[ty + i][tx] = W[(size_t)(k0 + ty + i) * N + n0 + tx];
    __syncthreads();
#pragma unroll
    for (int i = 0; i < 32; i += 8)
        WT[(size_t)(n0 + ty + i) * K + k0 + tx] = f2bf(tile[tx][ty + i]);
}

// ---------------------------------------------------------------- W1 pair-transpose -> bf16
__global__ __launch_bounds__(256) void transpose_pair_bf16(const float* __restrict__ W,
                                                           const float* __restrict__ scale,
                                                           unsigned short* __restrict__ WTP) {
    __shared__ float tile[32][33];
    int n0 = blockIdx.x * 32, k0 = blockIdx.y * 32;
    int tx = threadIdx.x & 31, ty = threadIdx.x >> 5;
#pragma unroll
    for (int i = 0; i < 32; i += 8)
        tile[ty + i][tx] = scale[k0 + ty + i] * W[(size_t)(k0 + ty + i) * (2 * DM) + n0 + tx];
    __syncthreads();
#pragma unroll
    for (int i = 0; i < 32; i += 8) {
        int c = n0 + ty + i;
        int cc = (c >= DM) ? c - DM : c;
        int h = (c >= DM) ? 1 : 0;
        int j = (cc >> 4) * 32 + h * 16 + (cc & 15);
        WTP[(size_t)j * DM + k0 + tx] = f2bf(tile[tx][ty + i]);
    }
}

// ---------------------------------------------------------------- u,v projections (2-stage)
__global__ __launch_bounds__(256) void uv_part(const float* __restrict__ W1,
                                               const float* __restrict__ g,
                                               const float* __restrict__ b,
                                               float* __restrict__ up,
                                               float* __restrict__ vp) {
    int nc = blockIdx.x & 3, kc = blockIdx.x >> 2;
    int n = nc * 256 + threadIdx.x;
    float su = 0.f, sv = 0.f;
#pragma unroll 8
    for (int k = kc * 64; k < kc * 64 + 64; ++k) {
        float w = W1[(size_t)k * (2 * DM) + n];
        su += g[k] * w;
        sv += b[k] * w;
    }
    up[kc * 1024 + n] = su;
    vp[kc * 1024 + n] = sv;
}

__global__ __launch_bounds__(256) void uv_reduce(const float* __restrict__ up,
                                                 const float* __restrict__ vp,
                                                 float* __restrict__ u,
                                                 float* __restrict__ v) {
    int n = blockIdx.x * 256 + threadIdx.x;
    float su = 0.f, sv = 0.f;
#pragma unroll
    for (int kc = 0; kc < 8; ++kc) {
        su += up[kc * 1024 + n];
        sv += vp[kc * 1024 + n];
    }
    u[n] = su;
    v[n] = sv;
}

// ---------------------------------------------------------------- GEMM1 big path: 8-wave quarter-tiles, BK=64 (R17/R19 best)
__global__ __launch_bounds__(512) void gemm1_silu_b(
    const unsigned short* __restrict__ X2b, const float2* __restrict__ st2,
    const float* __restrict__ uvec, const float* __restrict__ vvec,
    const unsigned short* __restrict__ BTP, const float* __restrict__ b1,
    unsigned short* __restrict__ G) {
    __shared__ __align__(16) unsigned short As[128 * 64];
    __shared__ __align__(16) unsigned short Bs[128 * 64];
    int tid = threadIdx.x;
    int wid = tid >> 6, lane = tid & 63;
    int wr = wid >> 2, wc = wid & 3;
    int l = lane & 15, kg = lane >> 4;
    int lin = blockIdx.y * 8 + blockIdx.x;
    int swz = (lin & 7) * 256 + (lin >> 3);
    int cb = swz & 7;
    int m0 = (swz >> 3) * 128;
    const unsigned short* Ab = X2b + (size_t)m0 * DM;
    const unsigned short* Bb = BTP + (size_t)(cb * 128) * DM;

    f32x4 acc[4][2] = {};
    int srow = tid >> 3, sq = tid & 7;

    for (int kt = 0; kt < DM / 64; ++kt) {
        int k0 = kt * 64;
#pragma unroll
        for (int i = 0; i < 2; ++i) {
            int row = srow + i * 64;
            size_t go = (size_t)row * DM + k0 + (sq ^ (row & 7)) * 8;
            int lo = (row * 64 + sq * 8);
            gload_lds16(Ab + go, As + lo);
            gload_lds16(Bb + go, Bs + lo);
        }
        __syncthreads();
#pragma unroll
        for (int kk = 0; kk < 2; ++kk) {
            int Q = kk * 4 + kg;
            bf16x8 af[4], bfr[2];
#pragma unroll
            for (int m = 0; m < 4; ++m) {
                int r = wr * 64 + m * 16 + l;
                af[m] = *(const bf16x8*)(As + r * 64 + (Q ^ (l & 7)) * 8);
            }
#pragma unroll
            for (int n = 0; n < 2; ++n) {
                int r = wc * 32 + n * 16 + l;
                bfr[n] = *(const bf16x8*)(Bs + r * 64 + (Q ^ (l & 7)) * 8);
            }
#pragma unroll
            for (int m = 0; m < 4; ++m)
#pragma unroll
                for (int n = 0; n < 2; ++n)
                    acc[m][n] = __builtin_amdgcn_mfma_f32_16x16x32_bf16(af[m], bfr[n], acc[m][n], 0, 0, 0);
        }
        __syncthreads();
    }

    int col = cb * 64 + wc * 16 + l;
    float u1 = uvec[col], u2 = uvec[col + DM];
    float c1 = vvec[col] + b1[col];
    float c2 = vvec[col + DM] + b1[col + DM];
#pragma unroll
    for (int m = 0; m < 4; ++m) {
        int row = m0 + wr * 64 + m * 16 + kg * 4;
#pragma unroll
        for (int r = 0; r < 4; ++r) {
            float2 s = st2[row + r];
            float rr = s.y, rm = s.x * s.y;
            float xv = acc[m][0][r] * rr - rm * u1 + c1;
            float gv = acc[m][1][r] * rr - rm * u2 + c2;
            float sv = xv / (1.0f + __expf(-xv)) * gv;
            G[(size_t)(row + r) * DM + col] = f2bf(sv);
        }
    }
}

// ---------------------------------------------------------------- GEMM1 fallback: fp32 A reg-staged (R10 form, 256 thr)
__global__ __launch_bounds__(256) void gemm1_silu_f(
    const float* __restrict__ X2, const float2* __restrict__ st2,
    const float* __restrict__ uvec, const float* __restrict__ vvec,
    const unsigned short* __restrict__ BTP, const float* __restrict__ b1,
    unsigned short* __restrict__ G) {
    __shared__ __align__(16) unsigned short As[128 * 32];
    __shared__ __align__(16) unsigned short Bs[128 * 32];
    int tid = threadIdx.x;
    int wid = tid >> 6, lane = tid & 63;
    int wr = wid >> 1, wc = wid & 1;
    int l = lane & 15, kg = lane >> 4;
    int lin = blockIdx.y * 8 + blockIdx.x;
    int swz = (lin & 7) * 256 + (lin >> 3);
    int cb = swz & 7;
    int m0 = (swz >> 3) * 128;
    const unsigned short* Bb = BTP + (size_t)(cb * 128) * DM;

    f32x4 acc[4][4] = {};

    for (int kt = 0; kt < DM / 32; ++kt) {
        int k0 = kt * 32;
#pragma unroll
        for (int i = 0; i < 2; ++i) {
            int c = i * 256 + tid;
            int row = c >> 2, q = c & 3;
            gload_lds16(Bb + (size_t)row * DM + k0 + q * 8, Bs + c * 8);
        }
#pragma unroll
        for (int i = 0; i < 2; ++i) {
            int c = i * 256 + tid;
            int row = c >> 2, q = c & 3;
            const float* src = X2 + (size_t)(m0 + row) * DM + k0 + q * 8;
            f32x4 v0 = *(const f32x4*)src;
            f32x4 v1 = *(const f32x4*)(src + 4);
            bf16x8 p;
#pragma unroll
            for (int j = 0; j < 4; ++j) p[j] = (short)f2bf(v0[j]);
#pragma unroll
            for (int j = 0; j < 4; ++j) p[4 + j] = (short)f2bf(v1[j]);
            *(bf16x8*)(As + row * 32 + q * 8) = p;
        }
        __syncthreads();
        bf16x8 af[4], bfr[4];
#pragma unroll
        for (int m = 0; m < 4; ++m)
            af[m] = *(const bf16x8*)(As + (wr * 64 + m * 16 + l) * 32 + kg * 8);
#pragma unroll
        for (int n = 0; n < 4; ++n)
            bfr[n] = *(const bf16x8*)(Bs + (wc * 64 + n * 16 + l) * 32 + kg * 8);
#pragma unroll
        for (int m = 0; m < 4; ++m)
#pragma unroll
            for (int n = 0; n < 4; ++n)
                acc[m][n] = __builtin_amdgcn_mfma_f32_16x16x32_bf16(af[m], bfr[n], acc[m][n], 0, 0, 0);
        __syncthreads();
    }
    float rr[4][4], rm[4][4];
#pragma unroll
    for (int m = 0; m < 4; ++m)
#pragma unroll
        for (int r = 0; r < 4; ++r) {
            float2 s = st2[m0 + wr * 64 + m * 16 + kg * 4 + r];
            rr[m][r] = s.y;
            rm[m][r] = s.x * s.y;
        }
#pragma unroll
    for (int p = 0; p < 2; ++p) {
        int col = cb * 64 + wc * 32 + p * 16 + l;
        float u1 = uvec[col], u2 = uvec[col + DM];
        float c1 = vvec[col] + b1[col];
        float c2 = vvec[col + DM] + b1[col + DM];
#pragma unroll
        for (int m = 0; m < 4; ++m) {
            int row = m0 + wr * 64 + m * 16 + kg * 4;
#pragma unroll
            for (int r = 0; r < 4; ++r) {
                float xv = acc[m][2 * p][r] * rr[m][r] - rm[m][r] * u1 + c1;
                float gv = acc[m][2 * p + 1][r] * rr[m][r] - rm[m][r] * u2 + c2;
                float sv = xv / (1.0f + __expf(-xv)) * gv;
                G[(size_t)(row + r) * DM + col] = f2bf(sv);
            }
        }
    }
}

// ---------------------------------------------------------------- GEMM2 + bias + residual (8-wave, BK=64)
// Big path (X2b != null): residual from bf16 X2b, PURE write to out (no RMW).
// Fallback: RMW on out.
__global__ __launch_bounds__(512) void gemm2_res(const unsigned short* __restrict__ A,
                                                 const unsigned short* __restrict__ BT,
                                                 const float* __restrict__ b2,
                                                 const unsigned short* __restrict__ X2b,
                                                 float* __restrict__ out) {
    __shared__ __align__(16) unsigned short As[128 * 64];
    __shared__ __align__(16) unsigned short Bs[128 * 64];
    int tid = threadIdx.x;
    int wid = tid >> 6, lane = tid & 63;
    int wr = wid >> 2, wc = wid & 3;
    int l = lane & 15, kg = lane >> 4;
    int lin = blockIdx.y * 4 + blockIdx.x;
    int swz = (lin & 7) * 128 + (lin >> 3);
    int cb = (swz & 3) * 128;
    int m0 = (swz >> 2) * 128;
    const unsigned short* Ab = A + (size_t)m0 * DM;
    const unsigned short* Bb = BT + (size_t)cb * DM;

    f32x4 acc[4][2] = {};
    int srow = tid >> 3, sq = tid & 7;

    for (int kt = 0; kt < DM / 64; ++kt) {
        int k0 = kt * 64;
#pragma unroll
        for (int i = 0; i < 2; ++i) {
            int row = srow + i * 64;
            size_t go = (size_t)row * DM + k0 + (sq ^ (row & 7)) * 8;
            int lo = (row * 64 + sq * 8);
            gload_lds16(Ab + go, As + lo);
            gload_lds16(Bb + go, Bs + lo);
        }
        __syncthreads();
#pragma unroll
        for (int kk = 0; kk < 2; ++kk) {
            int Q = kk * 4 + kg;
            bf16x8 af[4], bfr[2];
#pragma unroll
            for (int m = 0; m < 4; ++m) {
                int r = wr * 64 + m * 16 + l;
                af[m] = *(const bf16x8*)(As + r * 64 + (Q ^ (l & 7)) * 8);
            }
#pragma unroll
            for (int n = 0; n < 2; ++n) {
                int r = wc * 32 + n * 16 + l;
                bfr[n] = *(const bf16x8*)(Bs + r * 64 + (Q ^ (l & 7)) * 8);
            }
#pragma unroll
            for (int m = 0; m < 4; ++m)
#pragma unroll
                for (int n = 0; n < 2; ++n)
                    acc[m][n] = __builtin_amdgcn_mfma_f32_16x16x32_bf16(af[m], bfr[n], acc[m][n], 0, 0, 0);
        }
        __syncthreads();
    }
#pragma unroll
    for (int n = 0; n < 2; ++n) {
        int col = cb + wc * 32 + n * 16 + l;
        float bb = b2[col];
#pragma unroll
        for (int m = 0; m < 4; ++m) {
            int row = m0 + wr * 64 + m * 16 + kg * 4;
#pragma unroll
            for (int r = 0; r < 4; ++r) {
                size_t idx = (size_t)(row + r) * DM + col;
                float res = X2b ? bf2f(X2b[idx]) : out[idx];
                out[idx] = res + acc[m][n][r] + bb;
            }
        }
    }
}

// ---------------------------------------------------------------- launch
extern "C" void kernel_launch(void* const* d_in, const int* in_sizes, int n_in,
                              void* d_out, int out_size, void* d_ws, size_t ws_size,
                              hipStream_t stream) {
    const float* x    = (const float*)d_in[0];
    const float* ln1g = (const float*)d_in[1];
    const float* ln1b = (const float*)d_in[2];
    const float* Ar   = (const float*)d_in[3];
    const float* Ai   = (const float*)d_in[4];
    const float* Br   = (const float*)d_in[5];
    const float* Bi   = (const float*)d_in[6];
    const float* Cr   = (const float*)d_in[7];
    const float* Ci   = (const float*)d_in[8];
    const float* Dv   = (const float*)d_in[9];
    const float* ln2g = (const float*)d_in[10];
    const float* ln2b = (const float*)d_in[11];
    const float* W1   = (const float*)d_in[12];
    const float* b1   = (const float*)d_in[13];
    const float* W2   = (const float*)d_in[14];
    const float* b2   = (const float*)d_in[15];
    float* out = (float*)d_out;

    // workspace layout
    char* ws = (char*)d_ws;
    float*  taps   = (float*) (ws + 0x000000);   //  64 KB
    float2* stats  = (float2*)(ws + 0x010000);   // 256 KB (LN1)
    float2* stats2 = (float2*)(ws + 0x050000);   // 256 KB (LN2)
    unsigned short* W1TP = (unsigned short*)(ws + 0x090000);  // 1 MB
    unsigned short* W2T  = (unsigned short*)(ws + 0x190000);  // 512 KB
    float* uvec  = (float*)(ws + 0x210000);      // 4 KB
    float* vvec  = (float*)(ws + 0x211000);      // 4 KB
    float* upart = (float*)(ws + 0x212000);      // 32 KB
    float* vpart = (float*)(ws + 0x21A000);      // 32 KB
    unsigned short* G = (unsigned short*)(ws + 0x430000);     // 32 MB -> ends 0x2430000
    bool big = ws_size >= (size_t)0x4430000;     // need +32 MB for X2b
    unsigned short* X2b = big ? (unsigned short*)(ws + 0x2430000) : nullptr;

    gen_taps<<<2, 256, 0, stream>>>(Ar, Ai, Br, Bi, Cr, Ci, taps);
    ln_stats<<<NROWS / 4, 256, 0, stream>>>(x, stats);
    s4_conv<<<dim3(DM / 64, L_SEQ / 64, BATCH), 256, 0, stream>>>(x, stats, ln1g, ln1b, taps, Dv, out, X2b);
    if (big)
        ln2stats_b<<<NROWS / 4, 256, 0, stream>>>(X2b, stats2);
    else
        ln2pack<<<NROWS / 4, 256, 0, stream>>>(out, stats2);
    transpose_pair_bf16<<<dim3(1024 / 32, 512 / 32), 256, 0, stream>>>(W1, ln2g, W1TP);
    transpose_bf16<<<dim3(512 / 32, 512 / 32), 256, 0, stream>>>(W2, W2T, 512, 512);
    uv_part<<<32, 256, 0, stream>>>(W1, ln2g, ln2b, upart, vpart);
    uv_reduce<<<4, 256, 0, stream>>>(upart, vpart, uvec, vvec);
    if (big)
        gemm1_silu_b<<<dim3(8, NROWS / 128), 512, 0, stream>>>(X2b, stats2, uvec, vvec, W1TP, b1, G);
    else
        gemm1_silu_f<<<dim3(8, NROWS / 128), 256, 0, stream>>>(out, stats2, uvec, vvec, W1TP, b1, G);
    gemm2_res<<<dim3(4, NROWS / 128), 512, 0, stream>>>(G, W2T, b2, X2b, out);
}

// Round 21
// 137.668 us; speedup vs baseline: 1.4636x; 1.4636x over previous
//
#include <hip/hip_runtime.h>
#include <math.h>

#define L_SEQ 8192
#define DM 512
#define BATCH 4
#define NROWS (BATCH * L_SEQ)  // 32768
#define TAPS 32
#define EPS 1e-5f

typedef __attribute__((ext_vector_type(4))) float f32x4;
typedef __attribute__((ext_vector_type(8))) short bf16x8;
typedef __attribute__((ext_vector_type(4))) short short4v;
typedef __attribute__((ext_vector_type(8))) unsigned short ushort8;

__device__ inline unsigned short f2bf(float f) {
    unsigned u = __float_as_uint(f);
    u += 0x7FFF + ((u >> 16) & 1);   // round-to-nearest-even
    return (unsigned short)(u >> 16);
}

__device__ inline float bf2f(unsigned short u) {
    return __uint_as_float((unsigned)u << 16);
}

__device__ inline float wave_sum(float v) {
#pragma unroll
    for (int m = 32; m >= 1; m >>= 1) v += __shfl_xor(v, m);
    return v;
}

__device__ inline void gload_lds16(const void* g, void* l) {
    __builtin_amdgcn_global_load_lds(
        (const __attribute__((address_space(1))) void*)g,
        (__attribute__((address_space(3))) void*)l, 16, 0, 0);
}

// ---------------------------------------------------------------- taps
__global__ void gen_taps(const float* __restrict__ Ar, const float* __restrict__ Ai,
                         const float* __restrict__ Br, const float* __restrict__ Bi,
                         const float* __restrict__ Cr, const float* __restrict__ Ci,
                         float* __restrict__ taps) {
    int d = blockIdx.x * blockDim.x + threadIdx.x;
    if (d >= DM) return;
    float ar = Ar[d], ai = Ai[d];
    float pr = Cr[d] * Br[d] - Ci[d] * Bi[d];
    float pi = Cr[d] * Bi[d] + Ci[d] * Br[d];
#pragma unroll
    for (int s = 0; s < TAPS; ++s) {
        taps[s * DM + d] = pr;
        float nr = pr * ar - pi * ai;
        pi = pr * ai + pi * ar;
        pr = nr;
    }
}

// ---------------------------------------------------------------- LN1 row stats
__global__ __launch_bounds__(256) void ln_stats(const float* __restrict__ x,
                                                float2* __restrict__ stats) {
    int row = blockIdx.x * 4 + (threadIdx.x >> 6);
    int lane = threadIdx.x & 63;
    const float* xr = x + (size_t)row * DM;
    f32x4 v0 = *(const f32x4*)(xr + lane * 8);
    f32x4 v1 = *(const f32x4*)(xr + lane * 8 + 4);
    float s = v0[0] + v0[1] + v0[2] + v0[3] + v1[0] + v1[1] + v1[2] + v1[3];
    s = wave_sum(s);
    float mean = s * (1.0f / DM);
    float vs = 0.f;
#pragma unroll
    for (int j = 0; j < 4; ++j) { float a = v0[j] - mean; vs += a * a; }
#pragma unroll
    for (int j = 0; j < 4; ++j) { float a = v1[j] - mean; vs += a * a; }
    vs = wave_sum(vs);
    float rstd = rsqrtf(vs * (1.0f / DM) + EPS);
    if (lane == 0) stats[row] = make_float2(mean, rstd);
}

// ---------------------------------------------------------------- LN2 stats from bf16 X2b (big path)
__global__ __launch_bounds__(256) void ln2stats_b(const unsigned short* __restrict__ X2b,
                                                  float2* __restrict__ stats2) {
    int row = blockIdx.x * 4 + (threadIdx.x >> 6);
    int lane = threadIdx.x & 63;
    ushort8 u = *(const ushort8*)(X2b + (size_t)row * DM + lane * 8);
    float v[8];
#pragma unroll
    for (int j = 0; j < 8; ++j) v[j] = bf2f(u[j]);
    float s = 0.f;
#pragma unroll
    for (int j = 0; j < 8; ++j) s += v[j];
    s = wave_sum(s);
    float mean = s * (1.0f / DM);
    float vs = 0.f;
#pragma unroll
    for (int j = 0; j < 8; ++j) { float a = v[j] - mean; vs += a * a; }
    vs = wave_sum(vs);
    float rstd = rsqrtf(vs * (1.0f / DM) + EPS);
    if (lane == 0) stats2[row] = make_float2(mean, rstd);
}

// ---------------------------------------------------------------- LN2 stats from fp32 (fallback path)
__global__ __launch_bounds__(256) void ln2pack(const float* __restrict__ x2,
                                               float2* __restrict__ stats2) {
    int row = blockIdx.x * 4 + (threadIdx.x >> 6);
    int lane = threadIdx.x & 63;
    const float* xr = x2 + (size_t)row * DM;
    f32x4 v0 = *(const f32x4*)(xr + lane * 8);
    f32x4 v1 = *(const f32x4*)(xr + lane * 8 + 4);
    float s = v0[0] + v0[1] + v0[2] + v0[3] + v1[0] + v1[1] + v1[2] + v1[3];
    s = wave_sum(s);
    float mean = s * (1.0f / DM);
    float vs = 0.f;
#pragma unroll
    for (int j = 0; j < 4; ++j) { float a = v0[j] - mean; vs += a * a; }
#pragma unroll
    for (int j = 0; j < 4; ++j) { float a = v1[j] - mean; vs += a * a; }
    vs = wave_sum(vs);
    float rstd = rsqrtf(vs * (1.0f / DM) + EPS);
    if (lane == 0) stats2[row] = make_float2(mean, rstd);
}

// ---------------------------------------------------------------- S4 conv body (shared via macro-free duplication)
// Two compile-time variants below — NO runtime branch in the epilogue
// (R20 lesson: dual-path epilogue -> VGPR 244 -> occ 10% -> 82 us).

__global__ __launch_bounds__(256) void s4_conv_bf(
    const float* __restrict__ x, const float2* __restrict__ stats,
    const float* __restrict__ ln1g, const float* __restrict__ ln1b,
    const float* __restrict__ taps, const float* __restrict__ Dvec,
    unsigned short* __restrict__ X2b) {
    __shared__ __align__(16) float hbuf[96][64];
    __shared__ __align__(16) float kbuf[TAPS][64];
    int tid = threadIdx.x;
    int dc = blockIdx.x * 64;
    int t0 = blockIdx.y * 64;
    int b = blockIdx.z;
    const float* xb = x + (size_t)b * L_SEQ * DM;
    const float2* sb = stats + (size_t)b * L_SEQ;

#pragma unroll
    for (int i = 0; i < 2; ++i) {
        int idx = i * 256 + tid;
        int s = idx >> 4, c4i = (idx & 15) * 4;
        *(f32x4*)&kbuf[s][c4i] = *(const f32x4*)(taps + s * DM + dc + c4i);
    }
    int c4 = (tid & 15) * 4;
    int r0 = tid >> 4;
    f32x4 g4 = *(const f32x4*)(ln1g + dc + c4);
    f32x4 b4 = *(const f32x4*)(ln1b + dc + c4);
#pragma unroll
    for (int i = 0; i < 6; ++i) {
        int r = i * 16 + r0;
        int t = t0 - (TAPS - 1) + r;
        f32x4 h4 = {0.f, 0.f, 0.f, 0.f};
        if (t >= 0 && t < L_SEQ) {
            f32x4 xv = *(const f32x4*)(xb + (size_t)t * DM + dc + c4);
            float2 st = sb[t];
#pragma unroll
            for (int j = 0; j < 4; ++j) h4[j] = g4[j] * (xv[j] - st.x) * st.y + b4[j];
        }
        *(f32x4*)&hbuf[r][c4] = h4;
    }
    __syncthreads();

    int d4 = c4;
    int rbase = r0 * 4;
    f32x4 acc[4] = {{0.f,0.f,0.f,0.f},{0.f,0.f,0.f,0.f},{0.f,0.f,0.f,0.f},{0.f,0.f,0.f,0.f}};
    f32x4 tv[4];
    tv[0] = *(const f32x4*)&kbuf[TAPS - 1][d4];
    tv[1] = (f32x4){0.f,0.f,0.f,0.f};
    tv[2] = tv[1]; tv[3] = tv[1];
#pragma unroll
    for (int jj = 0; jj < TAPS + 3; ++jj) {
        f32x4 h4 = *(const f32x4*)&hbuf[rbase + jj][d4];
#pragma unroll
        for (int i = 0; i < 4; ++i)
#pragma unroll
            for (int j = 0; j < 4; ++j) acc[i][j] += tv[i][j] * h4[j];
        tv[3] = tv[2]; tv[2] = tv[1]; tv[1] = tv[0];
        int snew = TAPS - 2 - jj;
        if (snew >= 0) tv[0] = *(const f32x4*)&kbuf[snew][d4];
        else tv[0] = (f32x4){0.f,0.f,0.f,0.f};
    }

    f32x4 D4 = *(const f32x4*)(Dvec + dc + d4);
#pragma unroll
    for (int i = 0; i < 4; ++i) {
        int t = t0 + rbase + i;
        f32x4 xv = *(const f32x4*)(xb + (size_t)t * DM + dc + d4);
        f32x4 h4 = *(const f32x4*)&hbuf[rbase + i + TAPS - 1][d4];
        short4v pb;
#pragma unroll
        for (int j = 0; j < 4; ++j)
            pb[j] = (short)f2bf(xv[j] + acc[i][j] + D4[j] * h4[j]);
        *(short4v*)(X2b + ((size_t)(b * L_SEQ + t)) * DM + dc + d4) = pb;
    }
}

__global__ __launch_bounds__(256) void s4_conv_f32(
    const float* __restrict__ x, const float2* __restrict__ stats,
    const float* __restrict__ ln1g, const float* __restrict__ ln1b,
    const float* __restrict__ taps, const float* __restrict__ Dvec,
    float* __restrict__ out) {
    __shared__ __align__(16) float hbuf[96][64];
    __shared__ __align__(16) float kbuf[TAPS][64];
    int tid = threadIdx.x;
    int dc = blockIdx.x * 64;
    int t0 = blockIdx.y * 64;
    int b = blockIdx.z;
    const float* xb = x + (size_t)b * L_SEQ * DM;
    const float2* sb = stats + (size_t)b * L_SEQ;

#pragma unroll
    for (int i = 0; i < 2; ++i) {
        int idx = i * 256 + tid;
        int s = idx >> 4, c4i = (idx & 15) * 4;
        *(f32x4*)&kbuf[s][c4i] = *(const f32x4*)(taps + s * DM + dc + c4i);
    }
    int c4 = (tid & 15) * 4;
    int r0 = tid >> 4;
    f32x4 g4 = *(const f32x4*)(ln1g + dc + c4);
    f32x4 b4 = *(const f32x4*)(ln1b + dc + c4);
#pragma unroll
    for (int i = 0; i < 6; ++i) {
        int r = i * 16 + r0;
        int t = t0 - (TAPS - 1) + r;
        f32x4 h4 = {0.f, 0.f, 0.f, 0.f};
        if (t >= 0 && t < L_SEQ) {
            f32x4 xv = *(const f32x4*)(xb + (size_t)t * DM + dc + c4);
            float2 st = sb[t];
#pragma unroll
            for (int j = 0; j < 4; ++j) h4[j] = g4[j] * (xv[j] - st.x) * st.y + b4[j];
        }
        *(f32x4*)&hbuf[r][c4] = h4;
    }
    __syncthreads();

    int d4 = c4;
    int rbase = r0 * 4;
    f32x4 acc[4] = {{0.f,0.f,0.f,0.f},{0.f,0.f,0.f,0.f},{0.f,0.f,0.f,0.f},{0.f,0.f,0.f,0.f}};
    f32x4 tv[4];
    tv[0] = *(const f32x4*)&kbuf[TAPS - 1][d4];
    tv[1] = (f32x4){0.f,0.f,0.f,0.f};
    tv[2] = tv[1]; tv[3] = tv[1];
#pragma unroll
    for (int jj = 0; jj < TAPS + 3; ++jj) {
        f32x4 h4 = *(const f32x4*)&hbuf[rbase + jj][d4];
#pragma unroll
        for (int i = 0; i < 4; ++i)
#pragma unroll
            for (int j = 0; j < 4; ++j) acc[i][j] += tv[i][j] * h4[j];
        tv[3] = tv[2]; tv[2] = tv[1]; tv[1] = tv[0];
        int snew = TAPS - 2 - jj;
        if (snew >= 0) tv[0] = *(const f32x4*)&kbuf[snew][d4];
        else tv[0] = (f32x4){0.f,0.f,0.f,0.f};
    }

    f32x4 D4 = *(const f32x4*)(Dvec + dc + d4);
#pragma unroll
    for (int i = 0; i < 4; ++i) {
        int t = t0 + rbase + i;
        f32x4 xv = *(const f32x4*)(xb + (size_t)t * DM + dc + d4);
        f32x4 h4 = *(const f32x4*)&hbuf[rbase + i + TAPS - 1][d4];
        f32x4 o;
#pragma unroll
        for (int j = 0; j < 4; ++j) o[j] = xv[j] + acc[i][j] + D4[j] * h4[j];
        *(f32x4*)(out + ((size_t)(b * L_SEQ + t)) * DM + dc + d4) = o;
    }
}

// ---------------------------------------------------------------- W2 transpose -> bf16
__global__ __launch_bounds__(256) void transpose_bf16(const float* __restrict__ W,
                                                      unsigned short* __restrict__ WT,
                                                      int K, int N) {
    __shared__ float tile[32][33];
    int n0 = blockIdx.x * 32, k0 = blockIdx.y * 32;
    int tx = threadIdx.x & 31, ty = threadIdx.x >> 5;  // 32 x 8
#pragma unroll
    for (int i = 0; i < 32; i += 8)
        tile[ty + i][tx] = W[(size_t)(k0 + ty + i) * N + n0 + tx];
    __syncthreads();
#pragma unroll
    for (int i = 0; i < 32; i += 8)
        WT[(size_t)(n0 + ty + i) * K + k0 + tx] = f2bf(tile[tx][ty + i]);
}

// ---------------------------------------------------------------- W1 pair-transpose -> bf16
__global__ __launch_bounds__(256) void transpose_pair_bf16(const float* __restrict__ W,
                                                           const float* __restrict__ scale,
                                                           unsigned short* __restrict__ WTP) {
    __shared__ float tile[32][33];
    int n0 = blockIdx.x * 32, k0 = blockIdx.y * 32;
    int tx = threadIdx.x & 31, ty = threadIdx.x >> 5;
#pragma unroll
    for (int i = 0; i < 32; i += 8)
        tile[ty + i][tx] = scale[k0 + ty + i] * W[(size_t)(k0 + ty + i) * (2 * DM) + n0 + tx];
    __syncthreads();
#pragma unroll
    for (int i = 0; i < 32; i += 8) {
        int c = n0 + ty + i;
        int cc = (c >= DM) ? c - DM : c;
        int h = (c >= DM) ? 1 : 0;
        int j = (cc >> 4) * 32 + h * 16 + (cc & 15);
        WTP[(size_t)j * DM + k0 + tx] = f2bf(tile[tx][ty + i]);
    }
}

// ---------------------------------------------------------------- u,v projections (2-stage)
__global__ __launch_bounds__(256) void uv_part(const float* __restrict__ W1,
                                               const float* __restrict__ g,
                                               const float* __restrict__ b,
                                               float* __restrict__ up,
                                               float* __restrict__ vp) {
    int nc = blockIdx.x & 3, kc = blockIdx.x >> 2;
    int n = nc * 256 + threadIdx.x;
    float su = 0.f, sv = 0.f;
#pragma unroll 8
    for (int k = kc * 64; k < kc * 64 + 64; ++k) {
        float w = W1[(size_t)k * (2 * DM) + n];
        su += g[k] * w;
        sv += b[k] * w;
    }
    up[kc * 1024 + n] = su;
    vp[kc * 1024 + n] = sv;
}

__global__ __launch_bounds__(256) void uv_reduce(const float* __restrict__ up,
                                                 const float* __restrict__ vp,
                                                 float* __restrict__ u,
                                                 float* __restrict__ v) {
    int n = blockIdx.x * 256 + threadIdx.x;
    float su = 0.f, sv = 0.f;
#pragma unroll
    for (int kc = 0; kc < 8; ++kc) {
        su += up[kc * 1024 + n];
        sv += vp[kc * 1024 + n];
    }
    u[n] = su;
    v[n] = sv;
}

// ---------------------------------------------------------------- GEMM1 big path: 8-wave quarter-tiles, BK=64 (R17/R19 best)
__global__ __launch_bounds__(512) void gemm1_silu_b(
    const unsigned short* __restrict__ X2b, const float2* __restrict__ st2,
    const float* __restrict__ uvec, const float* __restrict__ vvec,
    const unsigned short* __restrict__ BTP, const float* __restrict__ b1,
    unsigned short* __restrict__ G) {
    __shared__ __align__(16) unsigned short As[128 * 64];
    __shared__ __align__(16) unsigned short Bs[128 * 64];
    int tid = threadIdx.x;
    int wid = tid >> 6, lane = tid & 63;
    int wr = wid >> 2, wc = wid & 3;
    int l = lane & 15, kg = lane >> 4;
    int lin = blockIdx.y * 8 + blockIdx.x;
    int swz = (lin & 7) * 256 + (lin >> 3);
    int cb = swz & 7;
    int m0 = (swz >> 3) * 128;
    const unsigned short* Ab = X2b + (size_t)m0 * DM;
    const unsigned short* Bb = BTP + (size_t)(cb * 128) * DM;

    f32x4 acc[4][2] = {};
    int srow = tid >> 3, sq = tid & 7;

    for (int kt = 0; kt < DM / 64; ++kt) {
        int k0 = kt * 64;
#pragma unroll
        for (int i = 0; i < 2; ++i) {
            int row = srow + i * 64;
            size_t go = (size_t)row * DM + k0 + (sq ^ (row & 7)) * 8;
            int lo = (row * 64 + sq * 8);
            gload_lds16(Ab + go, As + lo);
            gload_lds16(Bb + go, Bs + lo);
        }
        __syncthreads();
#pragma unroll
        for (int kk = 0; kk < 2; ++kk) {
            int Q = kk * 4 + kg;
            bf16x8 af[4], bfr[2];
#pragma unroll
            for (int m = 0; m < 4; ++m) {
                int r = wr * 64 + m * 16 + l;
                af[m] = *(const bf16x8*)(As + r * 64 + (Q ^ (l & 7)) * 8);
            }
#pragma unroll
            for (int n = 0; n < 2; ++n) {
                int r = wc * 32 + n * 16 + l;
                bfr[n] = *(const bf16x8*)(Bs + r * 64 + (Q ^ (l & 7)) * 8);
            }
#pragma unroll
            for (int m = 0; m < 4; ++m)
#pragma unroll
                for (int n = 0; n < 2; ++n)
                    acc[m][n] = __builtin_amdgcn_mfma_f32_16x16x32_bf16(af[m], bfr[n], acc[m][n], 0, 0, 0);
        }
        __syncthreads();
    }

    int col = cb * 64 + wc * 16 + l;
    float u1 = uvec[col], u2 = uvec[col + DM];
    float c1 = vvec[col] + b1[col];
    float c2 = vvec[col + DM] + b1[col + DM];
#pragma unroll
    for (int m = 0; m < 4; ++m) {
        int row = m0 + wr * 64 + m * 16 + kg * 4;
#pragma unroll
        for (int r = 0; r < 4; ++r) {
            float2 s = st2[row + r];
            float rr = s.y, rm = s.x * s.y;
            float xv = acc[m][0][r] * rr - rm * u1 + c1;
            float gv = acc[m][1][r] * rr - rm * u2 + c2;
            float sv = xv / (1.0f + __expf(-xv)) * gv;
            G[(size_t)(row + r) * DM + col] = f2bf(sv);
        }
    }
}

// ---------------------------------------------------------------- GEMM1 fallback: fp32 A reg-staged (R10 form, 256 thr)
__global__ __launch_bounds__(256) void gemm1_silu_f(
    const float* __restrict__ X2, const float2* __restrict__ st2,
    const float* __restrict__ uvec, const float* __restrict__ vvec,
    const unsigned short* __restrict__ BTP, const float* __restrict__ b1,
    unsigned short* __restrict__ G) {
    __shared__ __align__(16) unsigned short As[128 * 32];
    __shared__ __align__(16) unsigned short Bs[128 * 32];
    int tid = threadIdx.x;
    int wid = tid >> 6, lane = tid & 63;
    int wr = wid >> 1, wc = wid & 1;
    int l = lane & 15, kg = lane >> 4;
    int lin = blockIdx.y * 8 + blockIdx.x;
    int swz = (lin & 7) * 256 + (lin >> 3);
    int cb = swz & 7;
    int m0 = (swz >> 3) * 128;
    const unsigned short* Bb = BTP + (size_t)(cb * 128) * DM;

    f32x4 acc[4][4] = {};

    for (int kt = 0; kt < DM / 32; ++kt) {
        int k0 = kt * 32;
#pragma unroll
        for (int i = 0; i < 2; ++i) {
            int c = i * 256 + tid;
            int row = c >> 2, q = c & 3;
            gload_lds16(Bb + (size_t)row * DM + k0 + q * 8, Bs + c * 8);
        }
#pragma unroll
        for (int i = 0; i < 2; ++i) {
            int c = i * 256 + tid;
            int row = c >> 2, q = c & 3;
            const float* src = X2 + (size_t)(m0 + row) * DM + k0 + q * 8;
            f32x4 v0 = *(const f32x4*)src;
            f32x4 v1 = *(const f32x4*)(src + 4);
            bf16x8 p;
#pragma unroll
            for (int j = 0; j < 4; ++j) p[j] = (short)f2bf(v0[j]);
#pragma unroll
            for (int j = 0; j < 4; ++j) p[4 + j] = (short)f2bf(v1[j]);
            *(bf16x8*)(As + row * 32 + q * 8) = p;
        }
        __syncthreads();
        bf16x8 af[4], bfr[4];
#pragma unroll
        for (int m = 0; m < 4; ++m)
            af[m] = *(const bf16x8*)(As + (wr * 64 + m * 16 + l) * 32 + kg * 8);
#pragma unroll
        for (int n = 0; n < 4; ++n)
            bfr[n] = *(const bf16x8*)(Bs + (wc * 64 + n * 16 + l) * 32 + kg * 8);
#pragma unroll
        for (int m = 0; m < 4; ++m)
#pragma unroll
            for (int n = 0; n < 4; ++n)
                acc[m][n] = __builtin_amdgcn_mfma_f32_16x16x32_bf16(af[m], bfr[n], acc[m][n], 0, 0, 0);
        __syncthreads();
    }
    float rr[4][4], rm[4][4];
#pragma unroll
    for (int m = 0; m < 4; ++m)
#pragma unroll
        for (int r = 0; r < 4; ++r) {
            float2 s = st2[m0 + wr * 64 + m * 16 + kg * 4 + r];
            rr[m][r] = s.y;
            rm[m][r] = s.x * s.y;
        }
#pragma unroll
    for (int p = 0; p < 2; ++p) {
        int col = cb * 64 + wc * 32 + p * 16 + l;
        float u1 = uvec[col], u2 = uvec[col + DM];
        float c1 = vvec[col] + b1[col];
        float c2 = vvec[col + DM] + b1[col + DM];
#pragma unroll
        for (int m = 0; m < 4; ++m) {
            int row = m0 + wr * 64 + m * 16 + kg * 4;
#pragma unroll
            for (int r = 0; r < 4; ++r) {
                float xv = acc[m][2 * p][r] * rr[m][r] - rm[m][r] * u1 + c1;
                float gv = acc[m][2 * p + 1][r] * rr[m][r] - rm[m][r] * u2 + c2;
                float sv = xv / (1.0f + __expf(-xv)) * gv;
                G[(size_t)(row + r) * DM + col] = f2bf(sv);
            }
        }
    }
}

// ---------------------------------------------------------------- GEMM2 big path: residual from X2b, pure write
__global__ __launch_bounds__(512) void gemm2_res_b(const unsigned short* __restrict__ A,
                                                   const unsigned short* __restrict__ BT,
                                                   const float* __restrict__ b2,
                                                   const unsigned short* __restrict__ X2b,
                                                   float* __restrict__ out) {
    __shared__ __align__(16) unsigned short As[128 * 64];
    __shared__ __align__(16) unsigned short Bs[128 * 64];
    int tid = threadIdx.x;
    int wid = tid >> 6, lane = tid & 63;
    int wr = wid >> 2, wc = wid & 3;
    int l = lane & 15, kg = lane >> 4;
    int lin = blockIdx.y * 4 + blockIdx.x;
    int swz = (lin & 7) * 128 + (lin >> 3);
    int cb = (swz & 3) * 128;
    int m0 = (swz >> 2) * 128;
    const unsigned short* Ab = A + (size_t)m0 * DM;
    const unsigned short* Bb = BT + (size_t)cb * DM;

    f32x4 acc[4][2] = {};
    int srow = tid >> 3, sq = tid & 7;

    for (int kt = 0; kt < DM / 64; ++kt) {
        int k0 = kt * 64;
#pragma unroll
        for (int i = 0; i < 2; ++i) {
            int row = srow + i * 64;
            size_t go = (size_t)row * DM + k0 + (sq ^ (row & 7)) * 8;
            int lo = (row * 64 + sq * 8);
            gload_lds16(Ab + go, As + lo);
            gload_lds16(Bb + go, Bs + lo);
        }
        __syncthreads();
#pragma unroll
        for (int kk = 0; kk < 2; ++kk) {
            int Q = kk * 4 + kg;
            bf16x8 af[4], bfr[2];
#pragma unroll
            for (int m = 0; m < 4; ++m) {
                int r = wr * 64 + m * 16 + l;
                af[m] = *(const bf16x8*)(As + r * 64 + (Q ^ (l & 7)) * 8);
            }
#pragma unroll
            for (int n = 0; n < 2; ++n) {
                int r = wc * 32 + n * 16 + l;
                bfr[n] = *(const bf16x8*)(Bs + r * 64 + (Q ^ (l & 7)) * 8);
            }
#pragma unroll
            for (int m = 0; m < 4; ++m)
#pragma unroll
                for (int n = 0; n < 2; ++n)
                    acc[m][n] = __builtin_amdgcn_mfma_f32_16x16x32_bf16(af[m], bfr[n], acc[m][n], 0, 0, 0);
        }
        __syncthreads();
    }
#pragma unroll
    for (int n = 0; n < 2; ++n) {
        int col = cb + wc * 32 + n * 16 + l;
        float bb = b2[col];
#pragma unroll
        for (int m = 0; m < 4; ++m) {
            int row = m0 + wr * 64 + m * 16 + kg * 4;
#pragma unroll
            for (int r = 0; r < 4; ++r) {
                size_t idx = (size_t)(row + r) * DM + col;
                out[idx] = bf2f(X2b[idx]) + acc[m][n][r] + bb;
            }
        }
    }
}

// ---------------------------------------------------------------- GEMM2 fallback: RMW residual on fp32 out
__global__ __launch_bounds__(512) void gemm2_res_f(const unsigned short* __restrict__ A,
                                                   const unsigned short* __restrict__ BT,
                                                   const float* __restrict__ b2,
                                                   float* __restrict__ out) {
    __shared__ __align__(16) unsigned short As[128 * 64];
    __shared__ __align__(16) unsigned short Bs[128 * 64];
    int tid = threadIdx.x;
    int wid = tid >> 6, lane = tid & 63;
    int wr = wid >> 2, wc = wid & 3;
    int l = lane & 15, kg = lane >> 4;
    int lin = blockIdx.y * 4 + blockIdx.x;
    int swz = (lin & 7) * 128 + (lin >> 3);
    int cb = (swz & 3) * 128;
    int m0 = (swz >> 2) * 128;
    const unsigned short* Ab = A + (size_t)m0 * DM;
    const unsigned short* Bb = BT + (size_t)cb * DM;

    f32x4 acc[4][2] = {};
    int srow = tid >> 3, sq = tid & 7;

    for (int kt = 0; kt < DM / 64; ++kt) {
        int k0 = kt * 64;
#pragma unroll
        for (int i = 0; i < 2; ++i) {
            int row = srow + i * 64;
            size_t go = (size_t)row * DM + k0 + (sq ^ (row & 7)) * 8;
            int lo = (row * 64 + sq * 8);
            gload_lds16(Ab + go, As + lo);
            gload_lds16(Bb + go, Bs + lo);
        }
        __syncthreads();
#pragma unroll
        for (int kk = 0; kk < 2; ++kk) {
            int Q = kk * 4 + kg;
            bf16x8 af[4], bfr[2];
#pragma unroll
            for (int m = 0; m < 4; ++m) {
                int r = wr * 64 + m * 16 + l;
                af[m] = *(const bf16x8*)(As + r * 64 + (Q ^ (l & 7)) * 8);
            }
#pragma unroll
            for (int n = 0; n < 2; ++n) {
                int r = wc * 32 + n * 16 + l;
                bfr[n] = *(const bf16x8*)(Bs + r * 64 + (Q ^ (l & 7)) * 8);
            }
#pragma unroll
            for (int m = 0; m < 4; ++m)
#pragma unroll
                for (int n = 0; n < 2; ++n)
                    acc[m][n] = __builtin_amdgcn_mfma_f32_16x16x32_bf16(af[m], bfr[n], acc[m][n], 0, 0, 0);
        }
        __syncthreads();
    }
#pragma unroll
    for (int n = 0; n < 2; ++n) {
        int col = cb + wc * 32 + n * 16 + l;
        float bb = b2[col];
#pragma unroll
        for (int m = 0; m < 4; ++m) {
            int row = m0 + wr * 64 + m * 16 + kg * 4;
#pragma unroll
            for (int r = 0; r < 4; ++r) {
                size_t idx = (size_t)(row + r) * DM + col;
                out[idx] = out[idx] + acc[m][n][r] + bb;
            }
        }
    }
}

// ---------------------------------------------------------------- launch
extern "C" void kernel_launch(void* const* d_in, const int* in_sizes, int n_in,
                              void* d_out, int out_size, void* d_ws, size_t ws_size,
                              hipStream_t stream) {
    const float* x    = (const float*)d_in[0];
    const float* ln1g = (const float*)d_in[1];
    const float* ln1b = (const float*)d_in[2];
    const float* Ar   = (const float*)d_in[3];
    const float* Ai   = (const float*)d_in[4];
    const float* Br   = (const float*)d_in[5];
    const float* Bi   = (const float*)d_in[6];
    const float* Cr   = (const float*)d_in[7];
    const float* Ci   = (const float*)d_in[8];
    const float* Dv   = (const float*)d_in[9];
    const float* ln2g = (const float*)d_in[10];
    const float* ln2b = (const float*)d_in[11];
    const float* W1   = (const float*)d_in[12];
    const float* b1   = (const float*)d_in[13];
    const float* W2   = (const float*)d_in[14];
    const float* b2   = (const float*)d_in[15];
    float* out = (float*)d_out;

    // workspace layout
    char* ws = (char*)d_ws;
    float*  taps   = (float*) (ws + 0x000000);   //  64 KB
    float2* stats  = (float2*)(ws + 0x010000);   // 256 KB (LN1)
    float2* stats2 = (float2*)(ws + 0x050000);   // 256 KB (LN2)
    unsigned short* W1TP = (unsigned short*)(ws + 0x090000);  // 1 MB
    unsigned short* W2T  = (unsigned short*)(ws + 0x190000);  // 512 KB
    float* uvec  = (float*)(ws + 0x210000);      // 4 KB
    float* vvec  = (float*)(ws + 0x211000);      // 4 KB
    float* upart = (float*)(ws + 0x212000);      // 32 KB
    float* vpart = (float*)(ws + 0x21A000);      // 32 KB
    unsigned short* G = (unsigned short*)(ws + 0x430000);     // 32 MB -> ends 0x2430000
    bool big = ws_size >= (size_t)0x4430000;     // need +32 MB for X2b
    unsigned short* X2b = big ? (unsigned short*)(ws + 0x2430000) : nullptr;

    gen_taps<<<2, 256, 0, stream>>>(Ar, Ai, Br, Bi, Cr, Ci, taps);
    ln_stats<<<NROWS / 4, 256, 0, stream>>>(x, stats);
    if (big) {
        s4_conv_bf<<<dim3(DM / 64, L_SEQ / 64, BATCH), 256, 0, stream>>>(x, stats, ln1g, ln1b, taps, Dv, X2b);
        ln2stats_b<<<NROWS / 4, 256, 0, stream>>>(X2b, stats2);
    } else {
        s4_conv_f32<<<dim3(DM / 64, L_SEQ / 64, BATCH), 256, 0, stream>>>(x, stats, ln1g, ln1b, taps, Dv, out);
        ln2pack<<<NROWS / 4, 256, 0, stream>>>(out, stats2);
    }
    transpose_pair_bf16<<<dim3(1024 / 32, 512 / 32), 256, 0, stream>>>(W1, ln2g, W1TP);
    transpose_bf16<<<dim3(512 / 32, 512 / 32), 256, 0, stream>>>(W2, W2T, 512, 512);
    uv_part<<<32, 256, 0, stream>>>(W1, ln2g, ln2b, upart, vpart);
    uv_reduce<<<4, 256, 0, stream>>>(upart, vpart, uvec, vvec);
    if (big) {
        gemm1_silu_b<<<dim3(8, NROWS / 128), 512, 0, stream>>>(X2b, stats2, uvec, vvec, W1TP, b1, G);
        gemm2_res_b<<<dim3(4, NROWS / 128), 512, 0, stream>>>(G, W2T, b2, X2b, out);
    } else {
        gemm1_silu_f<<<dim3(8, NROWS / 128), 256, 0, stream>>>(out, stats2, uvec, vvec, W1TP, b1, G);
        gemm2_res_f<<<dim3(4, NROWS / 128), 512, 0, stream>>>(G, W2T, b2, out);
    }
}